// Round 15
// baseline (1433.452 us; speedup 1.0000x reference)
//
#include <hip/hip_runtime.h>
#include <stdint.h>

static constexpr int NB = 32, NH = 16, ND = 64, NS = 1024;
static constexpr int SZ = 262144;
static constexpr int NROW = NB * NH;            // 512
static constexpr long N4 = 67108864L;           // f32x4 per K (or V) store
static constexpr long HALF4 = 33554432L;        // 1/2: window/tail boundary
static constexpr int SPLIT_IDX = 131072;        // slots idx < SPLIT_IDX fixed by fixup path

typedef float f32x4 __attribute__((ext_vector_type(4)));

__device__ __forceinline__ uint32_t rotl32(uint32_t x, int r) { return (x << r) | (x >> (32 - r)); }

// Threefry-2x32-20 with key (0, 42): ks = [0, 42, 0x1BD11BDA^42 = 0x1BD11BF0]
__device__ __forceinline__ void tf2x32(uint32_t x0, uint32_t x1, uint32_t& o0, uint32_t& o1) {
  const uint32_t K1 = 42u, K2 = 0x1BD11BF0u;
  x1 += K1;
#define TFR(r) { x0 += x1; x1 = rotl32(x1, (r)); x1 ^= x0; }
  TFR(13) TFR(15) TFR(26) TFR(6)
  x0 += K1; x1 += K2 + 1u;
  TFR(17) TFR(29) TFR(16) TFR(24)
  x0 += K2; x1 += 2u;
  TFR(13) TFR(15) TFR(26) TFR(6)
  x1 += K1 + 3u;
  TFR(17) TFR(29) TFR(16) TFR(24)
  x0 += K1; x1 += K2 + 4u;
  TFR(13) TFR(15) TFR(26) TFR(6)
  x0 += K2; x1 += 5u;
#undef TFR
  o0 = x0; o1 = x1;
}

__device__ __forceinline__ uint32_t bits_of(uint32_t row, uint32_t s) {
  uint32_t o0, o1; tf2x32(0u, (row << 18) | s, o0, o1);
  return o0 ^ o1;
}

// precise gumbel (reference float path; decides the final selected set)
__device__ __forceinline__ float gumbel_precise(uint32_t row, uint32_t s) {
  uint32_t bits = bits_of(row, s);
  float f = __uint_as_float((bits >> 9) | 0x3f800000u) - 1.0f;
  float u = fmaxf(1e-12f, f + 1e-12f);
  float t = -logf(u);
  return -logf(t);
}

// raw uniform-in-[1,2) float for the cheap stage-1 filter (no transcendental)
__device__ __forceinline__ float uf_of(uint32_t row, uint32_t s) {
  return __uint_as_float((bits_of(row, s) >> 9) | 0x3f800000u);
}

// order-preserving float -> uint key
__device__ __forceinline__ uint32_t fkey(float v) {
  uint32_t u = __float_as_uint(v);
  return (u & 0x80000000u) ? ~u : (u | 0x80000000u);
}

// logw/wexp per (h,s); W[h] = sum_s wexp; outL = copy of Lst; winner = -1
__global__ void k_logw(const float* __restrict__ logit, float* __restrict__ logw,
                       float* __restrict__ wexp, float* __restrict__ outL,
                       int* __restrict__ winner, float* __restrict__ W) {
  __shared__ float sW[16];
  const int tid = threadIdx.x;
  if (tid < 16) sW[tid] = 0.f;
  __syncthreads();
  int s = blockIdx.x * 256 + tid;
  const float4* p = (const float4*)(logit + (size_t)s * NH);
  float4 a0 = p[0], a1 = p[1], a2 = p[2], a3 = p[3];
  float x[16] = {a0.x,a0.y,a0.z,a0.w, a1.x,a1.y,a1.z,a1.w,
                 a2.x,a2.y,a2.z,a2.w, a3.x,a3.y,a3.z,a3.w};
  float m = x[0];
#pragma unroll
  for (int h = 1; h < 16; ++h) m = fmaxf(m, x[h]);
  float acc = 0.f;
#pragma unroll
  for (int h = 0; h < 16; ++h) acc += expf(x[h] - m);
  float lse = logf(acc) + m;
  float wl[16];
#pragma unroll
  for (int h = 0; h < 16; ++h) {
    float lw = x[h] - lse;
    logw[(size_t)h * SZ + s] = lw;
    float e = expf(lw);
    wexp[(size_t)h * SZ + s] = e;
    wl[h] = e;
  }
#pragma unroll
  for (int h = 0; h < 16; ++h) {
    float v = wl[h];
#pragma unroll
    for (int off = 32; off; off >>= 1) v += __shfl_xor(v, off);
    if ((tid & 63) == 0) atomicAdd(&sW[h], v);
  }
  float4* q = (float4*)(outL + (size_t)s * NH);
  q[0] = a0; q[1] = a1; q[2] = a2; q[3] = a3;
  int4 mone = make_int4(-1, -1, -1, -1);
  int4* w = (int4*)(winner + (size_t)s * NH);
  w[0] = mone; w[1] = mone; w[2] = mone; w[3] = mone;
  __syncthreads();
  if (tid < 16) atomicAdd(&W[tid], sW[tid]);
}

#define FILT_T 512
#define HCAP 4096
// pure-VALU dense filter: 1024 blocks (one per (row, half)); 4 blocks/CU, no copy
// competition -> filter issue at full density. Candidates staged in LDS, bulk-written
// to a private global region (kernel boundary is the sync; no cross-block atomics).
__global__ void __launch_bounds__(FILT_T, 8) k_filter(
    const float* __restrict__ wexp, const float* __restrict__ Wsum,
    int* __restrict__ gcand, int* __restrict__ gcnt) {
  const int bid = blockIdx.x;          // 0..1023
  const int tid = threadIdx.x;
  const int row = bid >> 1, half = bid & 1;
  const int h = row & 15;
  const f32x4* we4 = (const f32x4*)(wexp + (size_t)h * SZ);
  __shared__ int cidx[HCAP];
  __shared__ int scnt;
  __shared__ float sNB;
  if (tid == 0) { scnt = 0; sNB = -4096.0f / Wsum[h]; }
  __syncthreads();
  const float nB = sNB;
  const float CThr = 1.9999996f;       // 2.0 minus 2 ulp slack: conservative necessary test
  const int gbase = half * (SZ / 8);   // 32768 f32x4-groups per half
  for (int g = gbase + tid; g < gbase + SZ / 8; g += FILT_T) {
    f32x4 w4 = we4[g];
    int s0 = g << 2;
    float u0 = uf_of(row, s0);
    float u1 = uf_of(row, s0 + 1);
    float u2 = uf_of(row, s0 + 2);
    float u3 = uf_of(row, s0 + 3);
    if (u0 >= fmaf(nB, w4.x, CThr)) { int p = atomicAdd(&scnt, 1); if (p < HCAP) cidx[p] = s0; }
    if (u1 >= fmaf(nB, w4.y, CThr)) { int p = atomicAdd(&scnt, 1); if (p < HCAP) cidx[p] = s0 + 1; }
    if (u2 >= fmaf(nB, w4.z, CThr)) { int p = atomicAdd(&scnt, 1); if (p < HCAP) cidx[p] = s0 + 2; }
    if (u3 >= fmaf(nB, w4.w, CThr)) { int p = atomicAdd(&scnt, 1); if (p < HCAP) cidx[p] = s0 + 3; }
  }
  __syncthreads();
  int c = min(scnt, HCAP);
  int* dst = gcand + (size_t)row * (2 * HCAP) + half * HCAP;
  for (int i = tid; i < c; i += FILT_T) dst[i] = cidx[i];
  if (tid == 0) gcnt[bid] = c;
}

// parallel descending-threshold find on wave 0 (caller syncs around it)
__device__ __forceinline__ void find_thresh(const uint32_t* hist, int nbins, int chunk,
                                            uint32_t need, int* outT, int tid) {
  if (tid < 64) {
    int hi = nbins - 1 - tid * chunk;
    uint32_t csum = 0;
    for (int j = 0; j < chunk; ++j) csum += hist[hi - j];
    uint32_t inc = csum;
#pragma unroll
    for (int off = 1; off < 64; off <<= 1) {
      uint32_t t = (uint32_t)__shfl_up((int)inc, off);
      if (tid >= off) inc += t;
    }
    uint32_t pre = inc - csum;
    if (pre < need && inc >= need) {
      uint32_t cum = pre; int T = hi - chunk + 1;
      for (int j = 0; j < chunk; ++j) {
        int b = hi - j;
        if (cum + hist[b] >= need) { T = b; break; }
        cum += hist[b];
      }
      *outT = T;
    }
  }
}

#define MEGA_T 512
#define SEL_BLKS 512
#define COPY_BLKS 2048
#define NCAND 6144
// k_finish: 512 stage2+attn blocks FIRST, then 2048 copy blocks covering [0, HALF4).
// Stage-2 = exact 11/11/10-bit radix select on precise keys over the filtered candidates;
// attn = two-pass (r11-proven) + winner atomics.
__global__ void __launch_bounds__(MEGA_T, 8) k_finish(
    const float* __restrict__ logw, const int* __restrict__ gcand,
    const int* __restrict__ gcnt, const float* __restrict__ qin,
    const float* __restrict__ Kst, const float* __restrict__ Vst,
    int* __restrict__ idx_sel, float* __restrict__ attn_ws,
    float* __restrict__ lerp_k, float* __restrict__ lerp_v, int* __restrict__ winner,
    f32x4* __restrict__ oK4, f32x4* __restrict__ oV4) {
  const int bid = blockIdx.x;
  const int tid = threadIdx.x;

  if (bid >= SEL_BLKS) {
    // ------- copy path: [0, HALF4); 8 batches of 4-deep (8 loads in flight) -------
    const f32x4* K4 = (const f32x4*)Kst;
    const f32x4* V4 = (const f32x4*)Vst;
    const long base = (long)(bid - SEL_BLKS) * MEGA_T + tid;
    const long stride = (long)COPY_BLKS * MEGA_T;         // 1,048,576 float4
    for (int r = 0; r < 8; ++r) {
      long i0 = base + (long)(4 * r) * stride;
      long i1 = i0 + stride, i2 = i0 + 2 * stride, i3 = i0 + 3 * stride;
      f32x4 k0 = __builtin_nontemporal_load(&K4[i0]);
      f32x4 k1 = __builtin_nontemporal_load(&K4[i1]);
      f32x4 k2 = __builtin_nontemporal_load(&K4[i2]);
      f32x4 k3 = __builtin_nontemporal_load(&K4[i3]);
      f32x4 v0 = __builtin_nontemporal_load(&V4[i0]);
      f32x4 v1 = __builtin_nontemporal_load(&V4[i1]);
      f32x4 v2 = __builtin_nontemporal_load(&V4[i2]);
      f32x4 v3 = __builtin_nontemporal_load(&V4[i3]);
      __builtin_nontemporal_store(k0, &oK4[i0]);
      __builtin_nontemporal_store(k1, &oK4[i1]);
      __builtin_nontemporal_store(k2, &oK4[i2]);
      __builtin_nontemporal_store(k3, &oK4[i3]);
      __builtin_nontemporal_store(v0, &oV4[i0]);
      __builtin_nontemporal_store(v1, &oV4[i1]);
      __builtin_nontemporal_store(v2, &oV4[i2]);
      __builtin_nontemporal_store(v3, &oV4[i3]);
    }
    return;
  }

  // ---------------- stage-2 + attn path (one row per block) ----------------
  const int row = bid;
  const int h = row & 15, b = row >> 4;
  const float* lw = logw + (size_t)h * SZ;
  int* outrow = idx_sel + (size_t)row * NS;

  __shared__ union {
    struct {
      int      cidx[NCAND];    // 24 KB candidate indices (loaded from gcand)
      uint32_t hist[2048];     //  8 KB
      uint16_t candA[2048];    //  4 KB (refs into cidx)
      uint16_t candB[256];
      uint16_t candC[64];
    } s;
    struct {
      int   sel_s[NS];
      float sc[NS];
      float red[MEGA_T];
      f32x4 pk4[8][16], pv4[8][16];
    } a;
  } u;
  __shared__ int ctl[8];   // 0:nsel 2:T 3:CA 4:CB 5:CC

  // load candidate halves from global (written by k_filter)
  const int c0 = min(gcnt[row * 2], HCAP);
  int c1 = min(gcnt[row * 2 + 1], HCAP);
  if (c0 + c1 > NCAND) c1 = NCAND - c0;       // statistically impossible; hard safety
  const int* src = gcand + (size_t)row * (2 * HCAP);
  for (int i = tid; i < c0; i += MEGA_T) u.s.cidx[i] = src[i];
  for (int i = tid; i < c1; i += MEGA_T) u.s.cidx[c0 + i] = src[HCAP + i];
  if (tid == 0) { ctl[0] = 0; ctl[3] = 0; ctl[4] = 0; ctl[5] = 0; }
  for (int i = tid; i < 2048; i += MEGA_T) u.s.hist[i] = 0;
  __syncthreads();
  const int C = c0 + c1;

  // ---- exact 11/11/10-bit radix select on precise keys (recomputed per pass) ----
  for (int ci = tid; ci < C; ci += MEGA_T) {
    int s = u.s.cidx[ci];
    uint32_t k = fkey(lw[s] + gumbel_precise(row, s));
    atomicAdd(&u.s.hist[k >> 21], 1u);
  }
  __syncthreads();
  find_thresh(u.s.hist, 2048, 32, (uint32_t)NS, &ctl[2], tid);
  __syncthreads();
  const int T0 = ctl[2];
  for (int ci = tid; ci < C; ci += MEGA_T) {
    int s = u.s.cidx[ci];
    uint32_t k = fkey(lw[s] + gumbel_precise(row, s));
    int bb = (int)(k >> 21);
    if (bb > T0)       { int p = atomicAdd(&ctl[0], 1); outrow[p] = s; }
    else if (bb == T0) { int c = atomicAdd(&ctl[3], 1); if (c < 2048) u.s.candA[c] = (uint16_t)ci; }
  }
  __syncthreads();
  const int CA = min(ctl[3], 2048);
  for (int i = tid; i < 2048; i += MEGA_T) u.s.hist[i] = 0;
  __syncthreads();
  for (int i = tid; i < CA; i += MEGA_T) {
    int s = u.s.cidx[u.s.candA[i]];
    uint32_t k = fkey(lw[s] + gumbel_precise(row, s));
    atomicAdd(&u.s.hist[(k >> 10) & 0x7FFu], 1u);
  }
  __syncthreads();
  find_thresh(u.s.hist, 2048, 32, (uint32_t)(NS - ctl[0]), &ctl[2], tid);
  __syncthreads();
  const int T1 = ctl[2];
  for (int i = tid; i < CA; i += MEGA_T) {
    int ci = u.s.candA[i];
    int s = u.s.cidx[ci];
    uint32_t k = fkey(lw[s] + gumbel_precise(row, s));
    int mid = (int)((k >> 10) & 0x7FFu);
    if (mid > T1)       { int p = atomicAdd(&ctl[0], 1); outrow[p] = s; }
    else if (mid == T1) { int c = atomicAdd(&ctl[4], 1); if (c < 256) u.s.candB[c] = (uint16_t)ci; }
  }
  __syncthreads();
  const int CB = min(ctl[4], 256);
  for (int i = tid; i < 1024; i += MEGA_T) u.s.hist[i] = 0;
  __syncthreads();
  for (int i = tid; i < CB; i += MEGA_T) {
    int s = u.s.cidx[u.s.candB[i]];
    uint32_t k = fkey(lw[s] + gumbel_precise(row, s));
    atomicAdd(&u.s.hist[k & 0x3FFu], 1u);
  }
  __syncthreads();
  find_thresh(u.s.hist, 1024, 16, (uint32_t)(NS - ctl[0]), &ctl[2], tid);
  __syncthreads();
  const int T2 = ctl[2];
  for (int i = tid; i < CB; i += MEGA_T) {
    int ci = u.s.candB[i];
    int s = u.s.cidx[ci];
    uint32_t k = fkey(lw[s] + gumbel_precise(row, s));
    int lo = (int)(k & 0x3FFu);
    if (lo > T2)       { int p = atomicAdd(&ctl[0], 1); outrow[p] = s; }
    else if (lo == T2) { int c = atomicAdd(&ctl[5], 1); if (c < 64) u.s.candC[c] = (uint16_t)ci; }
  }
  __syncthreads();
  if (tid == 0) {
    int need = NS - ctl[0];
    int cc = min(ctl[5], 64);
    for (int k = 0; k < need; ++k) {   // exact-key ties: smallest index first (top_k semantics)
      int best = 0x7fffffff, bi = 0;
      for (int j = 0; j < cc; ++j) { int s = u.s.cidx[u.s.candC[j]]; if (s < best) { best = s; bi = j; } }
      if (best == 0x7fffffff) best = 0;
      outrow[ctl[0] + k] = best;
      if (cc > 0) u.s.cidx[u.s.candC[bi]] = 0x7fffffff;
    }
  }
  __syncthreads();

  // ---------------- attn (two-pass, r11-proven): scores -> softmax -> lerp + winner ----
  const f32x4* K4 = (const f32x4*)Kst;
  const f32x4* V4 = (const f32x4*)Vst;
  const int lane = tid & 63, wv = tid >> 6;   // 8 waves
  const int sj = lane >> 3, dj = lane & 7;
  for (int i = tid; i < NS; i += MEGA_T) u.a.sel_s[i] = outrow[i];
  const f32x4* q4 = (const f32x4*)(qin + (size_t)row * ND);
  f32x4 qa = q4[dj * 2], qb = q4[dj * 2 + 1];
  __syncthreads();
  // phase 1: 8 scores per wave per iter, unroll 2
  for (int it = 0; it < 16; it += 2) {
    int i1 = it * 64 + wv * 8 + sj;
    int i2 = i1 + 64;
    int x1 = u.a.sel_s[i1], x2 = u.a.sel_s[i2];
    size_t b1 = ((size_t)x1 * NH + h) * 16 + dj * 2;
    size_t b2 = ((size_t)x2 * NH + h) * 16 + dj * 2;
    f32x4 ka1 = K4[b1], kb1 = K4[b1 + 1];
    f32x4 ka2 = K4[b2], kb2 = K4[b2 + 1];
    float p1 = ka1.x*qa.x + ka1.y*qa.y + ka1.z*qa.z + ka1.w*qa.w
             + kb1.x*qb.x + kb1.y*qb.y + kb1.z*qb.z + kb1.w*qb.w;
    float p2 = ka2.x*qa.x + ka2.y*qa.y + ka2.z*qa.z + ka2.w*qa.w
             + kb2.x*qb.x + kb2.y*qb.y + kb2.z*qb.z + kb2.w*qb.w;
#pragma unroll
    for (int off = 1; off < 8; off <<= 1) { p1 += __shfl_xor(p1, off); p2 += __shfl_xor(p2, off); }
    if (dj == 0) { u.a.sc[i1] = p1 * 0.125f; u.a.sc[i2] = p2 * 0.125f; }
  }
  __syncthreads();
  // softmax (2 scores per thread)
  float v1 = u.a.sc[tid], v2 = u.a.sc[tid + 512];
  u.a.red[tid] = fmaxf(v1, v2); __syncthreads();
  for (int s = 256; s; s >>= 1) { if (tid < s) u.a.red[tid] = fmaxf(u.a.red[tid], u.a.red[tid + s]); __syncthreads(); }
  float m = u.a.red[0]; __syncthreads();
  float e1 = expf(v1 - m), e2 = expf(v2 - m);
  u.a.red[tid] = e1 + e2; __syncthreads();
  for (int s = 256; s; s >>= 1) { if (tid < s) u.a.red[tid] += u.a.red[tid + s]; __syncthreads(); }
  float inv = 1.0f / u.a.red[0];
  float a1 = e1 * inv, a2 = e2 * inv;
  u.a.sc[tid] = a1; u.a.sc[tid + 512] = a2;
  attn_ws[(size_t)row * NS + tid] = a1;
  attn_ws[(size_t)row * NS + tid + 512] = a2;
  __syncthreads();
  // phase 2: lerp accumulation (ILP-2, 8 float4 loads in flight)
  f32x4 AK = 0.f, BK = 0.f, AV = 0.f, BV = 0.f;
  for (int it = 0; it < 16; it += 2) {
    int i1 = it * 64 + wv * 8 + sj;
    int i2 = i1 + 64;
    int x1 = u.a.sel_s[i1], x2 = u.a.sel_s[i2];
    float c1 = u.a.sc[i1], c2 = u.a.sc[i2];
    size_t b1 = ((size_t)x1 * NH + h) * 16 + dj * 2;
    size_t b2 = ((size_t)x2 * NH + h) * 16 + dj * 2;
    f32x4 k1a = K4[b1], k1b = K4[b1 + 1], v1a = V4[b1], v1b = V4[b1 + 1];
    f32x4 k2a = K4[b2], k2b = K4[b2 + 1], v2a = V4[b2], v2b = V4[b2 + 1];
    AK += c1 * k1a + c2 * k2a; BK += c1 * k1b + c2 * k2b;
    AV += c1 * v1a + c2 * v2a; BV += c1 * v1b + c2 * v2b;
  }
#pragma unroll
  for (int off = 8; off < 64; off <<= 1) {
    AK.x += __shfl_xor(AK.x, off); AK.y += __shfl_xor(AK.y, off);
    AK.z += __shfl_xor(AK.z, off); AK.w += __shfl_xor(AK.w, off);
    BK.x += __shfl_xor(BK.x, off); BK.y += __shfl_xor(BK.y, off);
    BK.z += __shfl_xor(BK.z, off); BK.w += __shfl_xor(BK.w, off);
    AV.x += __shfl_xor(AV.x, off); AV.y += __shfl_xor(AV.y, off);
    AV.z += __shfl_xor(AV.z, off); AV.w += __shfl_xor(AV.w, off);
    BV.x += __shfl_xor(BV.x, off); BV.y += __shfl_xor(BV.y, off);
    BV.z += __shfl_xor(BV.z, off); BV.w += __shfl_xor(BV.w, off);
  }
  if (sj == 0) {
    u.a.pk4[wv][dj * 2] = AK; u.a.pk4[wv][dj * 2 + 1] = BK;
    u.a.pv4[wv][dj * 2] = AV; u.a.pv4[wv][dj * 2 + 1] = BV;
  }
  __syncthreads();
  if (tid < 64) {
    float lk = 0.f, lv = 0.f;
    const float* pkf = (const float*)u.a.pk4;
    const float* pvf = (const float*)u.a.pv4;
#pragma unroll
    for (int ww = 0; ww < 8; ++ww) { lk += pkf[ww * 64 + tid]; lv += pvf[ww * 64 + tid]; }
    lerp_k[(size_t)row * ND + tid] = lk;
    lerp_v[(size_t)row * ND + tid] = lv;
  }
  // winner map: last-write-wins over b == max b per (idx,h)
  for (int i = tid; i < NS; i += MEGA_T) atomicMax(&winner[(size_t)u.a.sel_s[i] * NH + h], b);
}

// winning slots: record attn weight and fix outL (unique winner row per (idx,h))
__global__ void k_mark(const int* __restrict__ idx_sel, const float* __restrict__ attn_ws,
                       const int* __restrict__ winner, const float* __restrict__ Lst,
                       float* __restrict__ wa, float* __restrict__ outL) {
  int t = blockIdx.x * 256 + threadIdx.x;   // NROW*NS threads exactly
  int row = t >> 10, h = row & 15, b = row >> 4;
  int idx = idx_sel[t];
  size_t slot = (size_t)idx * NH + h;
  if (winner[slot] == b) {
    float a = attn_ws[t];
    wa[slot] = a;
    outL[slot] = 0.99f * Lst[slot] + a;
  }
}

#define TAIL_COPY_BLKS 4096
// heterogeneous tail: blend-fused copy of the SECOND half of K,V (first 4096 blocks),
// then 131072 tiny fixup blocks (first-half winner RMW) backfill as copy blocks retire.
__global__ void __launch_bounds__(256) k_tail(const f32x4* __restrict__ K4,
    const f32x4* __restrict__ V4, const int* __restrict__ winner,
    const float* __restrict__ wa, const f32x4* __restrict__ LK4,
    const f32x4* __restrict__ LV4, const int* __restrict__ idx_sel,
    const float* __restrict__ attn_ws, f32x4* __restrict__ oK4, f32x4* __restrict__ oV4) {
  const int bid = blockIdx.x;
  if (bid < TAIL_COPY_BLKS) {
    // ------- blend-fused copy of [HALF4, N4): 8 batches of 4-deep -------
    const long base = HALF4 + (long)bid * 256 + threadIdx.x;
    const long stride = (long)TAIL_COPY_BLKS * 256;       // 1,048,576 float4
    for (int r = 0; r < 8; ++r) {
      long i0 = base + (long)(4 * r) * stride;
      long i1 = i0 + stride, i2 = i0 + 2 * stride, i3 = i0 + 3 * stride;
      int s0 = (int)(i0 >> 4), s1 = (int)(i1 >> 4), s2 = (int)(i2 >> 4), s3 = (int)(i3 >> 4);
      int w0 = winner[s0], w1 = winner[s1], w2 = winner[s2], w3 = winner[s3];
      f32x4 k0 = __builtin_nontemporal_load(&K4[i0]);
      f32x4 k1 = __builtin_nontemporal_load(&K4[i1]);
      f32x4 k2 = __builtin_nontemporal_load(&K4[i2]);
      f32x4 k3 = __builtin_nontemporal_load(&K4[i3]);
      f32x4 v0 = __builtin_nontemporal_load(&V4[i0]);
      f32x4 v1 = __builtin_nontemporal_load(&V4[i1]);
      f32x4 v2 = __builtin_nontemporal_load(&V4[i2]);
      f32x4 v3 = __builtin_nontemporal_load(&V4[i3]);
      if (w0 >= 0) {
        float a = wa[s0]; int rr = (w0 << 4) | (s0 & 15); float o = 1.0f - a;
        k0 = o * k0 + a * LK4[((long)rr << 4) + (i0 & 15)];
        v0 = o * v0 + a * LV4[((long)rr << 4) + (i0 & 15)];
      }
      if (w1 >= 0) {
        float a = wa[s1]; int rr = (w1 << 4) | (s1 & 15); float o = 1.0f - a;
        k1 = o * k1 + a * LK4[((long)rr << 4) + (i1 & 15)];
        v1 = o * v1 + a * LV4[((long)rr << 4) + (i1 & 15)];
      }
      if (w2 >= 0) {
        float a = wa[s2]; int rr = (w2 << 4) | (s2 & 15); float o = 1.0f - a;
        k2 = o * k2 + a * LK4[((long)rr << 4) + (i2 & 15)];
        v2 = o * v2 + a * LV4[((long)rr << 4) + (i2 & 15)];
      }
      if (w3 >= 0) {
        float a = wa[s3]; int rr = (w3 << 4) | (s3 & 15); float o = 1.0f - a;
        k3 = o * k3 + a * LK4[((long)rr << 4) + (i3 & 15)];
        v3 = o * v3 + a * LV4[((long)rr << 4) + (i3 & 15)];
      }
      __builtin_nontemporal_store(k0, &oK4[i0]);
      __builtin_nontemporal_store(k1, &oK4[i1]);
      __builtin_nontemporal_store(k2, &oK4[i2]);
      __builtin_nontemporal_store(k3, &oK4[i3]);
      __builtin_nontemporal_store(v0, &oV4[i0]);
      __builtin_nontemporal_store(v1, &oV4[i1]);
      __builtin_nontemporal_store(v2, &oV4[i2]);
      __builtin_nontemporal_store(v3, &oV4[i3]);
    }
    return;
  }
  // ------- fixup path: winner-slot RMW for first-half slots; one wave per (row,i) -------
  int g = (bid - TAIL_COPY_BLKS) * 4 + (threadIdx.x >> 6);
  int lane = threadIdx.x & 63;
  int row = g >> 10, i = g & 1023;
  int h = row & 15, b = row >> 4;
  int idx = idx_sel[(size_t)row * NS + i];
  if (idx >= SPLIT_IDX) return;               // second half handled by blend-copy above
  size_t slot = (size_t)idx * NH + h;
  if (winner[slot] != b) return;
  float a = attn_ws[(size_t)row * NS + i];
  size_t base = slot * (size_t)ND + lane;
  float kv = ((const float*)K4)[base], vv = ((const float*)V4)[base];
  float lk = ((const float*)LK4)[(size_t)row * ND + lane];
  float lv = ((const float*)LV4)[(size_t)row * ND + lane];
  float o = 1.0f - a;
  ((float*)oK4)[base] = o * kv + a * lk;
  ((float*)oV4)[base] = o * vv + a * lv;
}

extern "C" void kernel_launch(void* const* d_in, const int* in_sizes, int n_in,
                              void* d_out, int out_size, void* d_ws, size_t ws_size,
                              hipStream_t stream) {
  const float* q   = (const float*)d_in[0];
  const float* Kst = (const float*)d_in[1];
  const float* Vst = (const float*)d_in[2];
  const float* Lst = (const float*)d_in[3];

  float* out    = (float*)d_out;
  float* out_lk = out;                        // (B,H,D)
  float* out_lv = out + 32768;
  float* outK   = out + 65536;                // (SIZE,H,D)
  float* outV   = outK + 268435456;
  float* outL   = outV + 268435456;           // (SIZE,H)

  char* ws = (char*)d_ws;
  float* logw   = (float*)ws;                         // 16 MB (H,SIZE)
  float* wexp   = (float*)(ws + (16ull << 20));       // 16 MB (H,SIZE)
  int*   idxsel = (int*)(ws + (32ull << 20));         //  2 MB (NROW,NS)
  float* attn   = (float*)(ws + (34ull << 20));       //  2 MB
  int*   winner = (int*)(ws + (36ull << 20));         // 16 MB (SIZE,H)
  float* wa     = (float*)(ws + (52ull << 20));       // 16 MB (SIZE,H)
  int*   gcand  = (int*)(ws + (68ull << 20));         // 16 MB (NROW, 2*HCAP)
  int*   gcnt   = (int*)(ws + (84ull << 20));         //  4 KB (1024)
  float* Wsum   = (float*)(ws + (84ull << 20) + 8192);// 64 B  (H)

  hipMemsetAsync(Wsum, 0, 16 * sizeof(float), stream);
  k_logw<<<SZ / 256, 256, 0, stream>>>(Lst, logw, wexp, outL, winner, Wsum);
  k_filter<<<2 * NROW, FILT_T, 0, stream>>>(wexp, Wsum, gcand, gcnt);
  k_finish<<<SEL_BLKS + COPY_BLKS, MEGA_T, 0, stream>>>(logw, gcand, gcnt, q, Kst, Vst,
                                                        idxsel, attn, out_lk, out_lv, winner,
                                                        (f32x4*)outK, (f32x4*)outV);
  k_mark<<<NROW * NS / 256, 256, 0, stream>>>(idxsel, attn, winner, Lst, wa, outL);
  k_tail<<<TAIL_COPY_BLKS + NROW * NS / 4, 256, 0, stream>>>(
      (const f32x4*)Kst, (const f32x4*)Vst, winner, wa,
      (const f32x4*)out_lk, (const f32x4*)out_lv, idxsel, attn,
      (f32x4*)outK, (f32x4*)outV);
}

// Round 16
// 1138.974 us; speedup vs baseline: 1.2585x; 1.2585x over previous
//
#include <hip/hip_runtime.h>
#include <stdint.h>

static constexpr int NB = 32, NH = 16, ND = 64, NS = 1024;
static constexpr int SZ = 262144;
static constexpr int NROW = NB * NH;            // 512
static constexpr long N4 = 67108864L;           // f32x4 per K (or V) store
static constexpr long HALF4 = 33554432L;        // half of N4 (copied during select window)
static constexpr int SPLIT_IDX = 131072;        // slots with idx < SPLIT_IDX fixed by fixup path

typedef float f32x4 __attribute__((ext_vector_type(4)));

__device__ __forceinline__ uint32_t rotl32(uint32_t x, int r) { return __builtin_rotateleft32(x, r); }

// Threefry-2x32-20 with key (0, 42): ks = [0, 42, 0x1BD11BDA^42 = 0x1BD11BF0]
__device__ __forceinline__ void tf2x32(uint32_t x0, uint32_t x1, uint32_t& o0, uint32_t& o1) {
  const uint32_t K1 = 42u, K2 = 0x1BD11BF0u;
  x1 += K1;
#define TFR(r) { x0 += x1; x1 = rotl32(x1, (r)); x1 ^= x0; }
  TFR(13) TFR(15) TFR(26) TFR(6)
  x0 += K1; x1 += K2 + 1u;
  TFR(17) TFR(29) TFR(16) TFR(24)
  x0 += K2; x1 += 2u;
  TFR(13) TFR(15) TFR(26) TFR(6)
  x1 += K1 + 3u;
  TFR(17) TFR(29) TFR(16) TFR(24)
  x0 += K1; x1 += K2 + 4u;
  TFR(13) TFR(15) TFR(26) TFR(6)
  x0 += K2; x1 += 5u;
#undef TFR
  o0 = x0; o1 = x1;
}

__device__ __forceinline__ uint32_t bits_of(uint32_t row, uint32_t s) {
  uint32_t o0, o1; tf2x32(0u, (row << 18) | s, o0, o1);
  return o0 ^ o1;
}

// precise gumbel (reference float path; decides the final selected set)
__device__ __forceinline__ float gumbel_precise(uint32_t row, uint32_t s) {
  uint32_t bits = bits_of(row, s);
  float f = __uint_as_float((bits >> 9) | 0x3f800000u) - 1.0f;
  float u = fmaxf(1e-12f, f + 1e-12f);
  float t = -logf(u);
  return -logf(t);
}

// raw uniform-in-[1,2) float for the cheap stage-1 filter (no transcendental)
__device__ __forceinline__ float uf_of(uint32_t row, uint32_t s) {
  return __uint_as_float((bits_of(row, s) >> 9) | 0x3f800000u);
}

// order-preserving float -> uint key
__device__ __forceinline__ uint32_t fkey(float v) {
  uint32_t u = __float_as_uint(v);
  return (u & 0x80000000u) ? ~u : (u | 0x80000000u);
}

// logw/wexp per (h,s); W[h] = sum_s wexp; outL = copy of Lst; winner = -1
__global__ void k_logw(const float* __restrict__ logit, float* __restrict__ logw,
                       float* __restrict__ wexp, float* __restrict__ outL,
                       int* __restrict__ winner, float* __restrict__ W) {
  __shared__ float sW[16];
  const int tid = threadIdx.x;
  if (tid < 16) sW[tid] = 0.f;
  __syncthreads();
  int s = blockIdx.x * 256 + tid;
  const float4* p = (const float4*)(logit + (size_t)s * NH);
  float4 a0 = p[0], a1 = p[1], a2 = p[2], a3 = p[3];
  float x[16] = {a0.x,a0.y,a0.z,a0.w, a1.x,a1.y,a1.z,a1.w,
                 a2.x,a2.y,a2.z,a2.w, a3.x,a3.y,a3.z,a3.w};
  float m = x[0];
#pragma unroll
  for (int h = 1; h < 16; ++h) m = fmaxf(m, x[h]);
  float acc = 0.f;
#pragma unroll
  for (int h = 0; h < 16; ++h) acc += expf(x[h] - m);
  float lse = logf(acc) + m;
  float wl[16];
#pragma unroll
  for (int h = 0; h < 16; ++h) {
    float lw = x[h] - lse;
    logw[(size_t)h * SZ + s] = lw;
    float e = expf(lw);
    wexp[(size_t)h * SZ + s] = e;
    wl[h] = e;
  }
#pragma unroll
  for (int h = 0; h < 16; ++h) {
    float v = wl[h];
#pragma unroll
    for (int off = 32; off; off >>= 1) v += __shfl_xor(v, off);
    if ((tid & 63) == 0) atomicAdd(&sW[h], v);
  }
  float4* q = (float4*)(outL + (size_t)s * NH);
  q[0] = a0; q[1] = a1; q[2] = a2; q[3] = a3;
  int4 mone = make_int4(-1, -1, -1, -1);
  int4* w = (int4*)(winner + (size_t)s * NH);
  w[0] = mone; w[1] = mone; w[2] = mone; w[3] = mone;
  __syncthreads();
  if (tid < 16) atomicAdd(&W[tid], sW[tid]);
}

// parallel descending-threshold find on wave 0 (caller syncs around it)
__device__ __forceinline__ void find_thresh(const uint32_t* hist, int nbins, int chunk,
                                            uint32_t need, int* outT, int tid) {
  if (tid < 64) {
    int hi = nbins - 1 - tid * chunk;
    uint32_t csum = 0;
    for (int j = 0; j < chunk; ++j) csum += hist[hi - j];
    uint32_t inc = csum;
#pragma unroll
    for (int off = 1; off < 64; off <<= 1) {
      uint32_t t = (uint32_t)__shfl_up((int)inc, off);
      if (tid >= off) inc += t;
    }
    uint32_t pre = inc - csum;
    if (pre < need && inc >= need) {
      uint32_t cum = pre; int T = hi - chunk + 1;
      for (int j = 0; j < chunk; ++j) {
        int b = hi - j;
        if (cum + hist[b] >= need) { T = b; break; }
        cum += hist[b];
      }
      *outT = T;
    }
  }
}

#define MEGA_T 512
#define SEL_BLKS 512
#define COPY_BLKS 2048
#define NCAND 5120
// mega: 512 select+attn blocks FIRST, then 2048 copy blocks covering the FIRST HALF of
// K and V (pure streaming, manual 4-deep batching). Second half is blend-copied by
// k_tail; first-half winners fixed by k_tail's fixup blocks.
__global__ void __launch_bounds__(MEGA_T, 8) k_mega(
    const float* __restrict__ logw, const float* __restrict__ wexp,
    const float* __restrict__ Wsum, const float* __restrict__ qin,
    const float* __restrict__ Kst, const float* __restrict__ Vst,
    int* __restrict__ idx_sel, float* __restrict__ attn_ws,
    float* __restrict__ lerp_k, float* __restrict__ lerp_v, int* __restrict__ winner,
    f32x4* __restrict__ oK4, f32x4* __restrict__ oV4) {
  const int bid = blockIdx.x;
  const int tid = threadIdx.x;

  if (bid >= SEL_BLKS) {
    // ------- copy path: first 1/2 of K,V; 8 batches of 4-deep (8 loads in flight) -------
    const f32x4* K4 = (const f32x4*)Kst;
    const f32x4* V4 = (const f32x4*)Vst;
    const long base = (long)(bid - SEL_BLKS) * MEGA_T + tid;
    const long stride = (long)COPY_BLKS * MEGA_T;         // 1,048,576 float4
    for (int r = 0; r < 8; ++r) {
      long i0 = base + (long)(4 * r) * stride;
      long i1 = i0 + stride, i2 = i0 + 2 * stride, i3 = i0 + 3 * stride;
      f32x4 k0 = __builtin_nontemporal_load(&K4[i0]);
      f32x4 k1 = __builtin_nontemporal_load(&K4[i1]);
      f32x4 k2 = __builtin_nontemporal_load(&K4[i2]);
      f32x4 k3 = __builtin_nontemporal_load(&K4[i3]);
      f32x4 v0 = __builtin_nontemporal_load(&V4[i0]);
      f32x4 v1 = __builtin_nontemporal_load(&V4[i1]);
      f32x4 v2 = __builtin_nontemporal_load(&V4[i2]);
      f32x4 v3 = __builtin_nontemporal_load(&V4[i3]);
      __builtin_nontemporal_store(k0, &oK4[i0]);
      __builtin_nontemporal_store(k1, &oK4[i1]);
      __builtin_nontemporal_store(k2, &oK4[i2]);
      __builtin_nontemporal_store(k3, &oK4[i3]);
      __builtin_nontemporal_store(v0, &oV4[i0]);
      __builtin_nontemporal_store(v1, &oV4[i1]);
      __builtin_nontemporal_store(v2, &oV4[i2]);
      __builtin_nontemporal_store(v3, &oV4[i3]);
    }
    return;
  }

  // ---------------- select + attn path (one row per block) ----------------
  const int row = bid;
  const int h = row & 15, b = row >> 4;
  const float* lw = logw + (size_t)h * SZ;
  const f32x4* we4 = (const f32x4*)(wexp + (size_t)h * SZ);
  int* outrow = idx_sel + (size_t)row * NS;

  __shared__ union {
    struct {
      int      cidx[NCAND];    // 20 KB candidate indices
      uint32_t hist[2048];     //  8 KB
      uint16_t candA[2048];    //  4 KB (refs into cidx)
      uint16_t candB[256];
      uint16_t candC[64];
    } s;
    struct {
      int   sel_s[NS];
      float sc[NS];
      float red[MEGA_T];
      f32x4 pk4[8][16], pv4[8][16];
    } a;
  } u;
  __shared__ int ctl[8];   // 0:nsel 1:ncand 2:T 3:CA 4:CB 5:CC
  __shared__ float sNB;

  if (tid == 0) {
    float Wh = Wsum[h];
    // analytic vlo = log(Wh/4096) targets filter rank ~4096.
    // exact test: u >= 2^(nA*wexp). cheap NECESSARY test (2^x >= 1+x*ln2):
    //   uf >= 2 + nB*wexp, nB = -4096/Wh (uf in [1,2))
    sNB = -4096.0f / Wh;
    ctl[1] = 0;
  }
  __syncthreads();
  const float nB = sNB;
  const float CThr = 1.9999996f;   // 2.0 minus 2 ulp slack: keeps the test conservative

  // ---- stage 1: full pass, NO transcendental: threefry + fma + cmp, ILP-4 ----
  for (int g = tid; g < SZ / 4; g += MEGA_T) {
    f32x4 w4 = we4[g];   // cached: 16 MB/head set is L2/L3-resident with 32-way reuse
    int s0 = g << 2;
    float u0 = uf_of(row, s0);
    float u1 = uf_of(row, s0 + 1);
    float u2 = uf_of(row, s0 + 2);
    float u3 = uf_of(row, s0 + 3);
    if (u0 >= fmaf(nB, w4.x, CThr)) { int p = atomicAdd(&ctl[1], 1); if (p < NCAND) u.s.cidx[p] = s0; }
    if (u1 >= fmaf(nB, w4.y, CThr)) { int p = atomicAdd(&ctl[1], 1); if (p < NCAND) u.s.cidx[p] = s0 + 1; }
    if (u2 >= fmaf(nB, w4.z, CThr)) { int p = atomicAdd(&ctl[1], 1); if (p < NCAND) u.s.cidx[p] = s0 + 2; }
    if (u3 >= fmaf(nB, w4.w, CThr)) { int p = atomicAdd(&ctl[1], 1); if (p < NCAND) u.s.cidx[p] = s0 + 3; }
  }
  __syncthreads();
  const int C = min(ctl[1], NCAND);

  // ---- stage 2: exact 11/11/10-bit radix select on precise keys (recomputed per pass) ----
  for (int i = tid; i < 2048; i += MEGA_T) u.s.hist[i] = 0;
  if (tid == 0) { ctl[0] = 0; ctl[3] = 0; ctl[4] = 0; ctl[5] = 0; }
  __syncthreads();
  for (int ci = tid; ci < C; ci += MEGA_T) {
    int s = u.s.cidx[ci];
    uint32_t k = fkey(lw[s] + gumbel_precise(row, s));
    atomicAdd(&u.s.hist[k >> 21], 1u);
  }
  __syncthreads();
  find_thresh(u.s.hist, 2048, 32, (uint32_t)NS, &ctl[2], tid);
  __syncthreads();
  const int T0 = ctl[2];
  for (int ci = tid; ci < C; ci += MEGA_T) {
    int s = u.s.cidx[ci];
    uint32_t k = fkey(lw[s] + gumbel_precise(row, s));
    int bb = (int)(k >> 21);
    if (bb > T0)       { int p = atomicAdd(&ctl[0], 1); outrow[p] = s; }
    else if (bb == T0) { int c = atomicAdd(&ctl[3], 1); if (c < 2048) u.s.candA[c] = (uint16_t)ci; }
  }
  __syncthreads();
  const int CA = min(ctl[3], 2048);
  for (int i = tid; i < 2048; i += MEGA_T) u.s.hist[i] = 0;
  __syncthreads();
  for (int i = tid; i < CA; i += MEGA_T) {
    int s = u.s.cidx[u.s.candA[i]];
    uint32_t k = fkey(lw[s] + gumbel_precise(row, s));
    atomicAdd(&u.s.hist[(k >> 10) & 0x7FFu], 1u);
  }
  __syncthreads();
  find_thresh(u.s.hist, 2048, 32, (uint32_t)(NS - ctl[0]), &ctl[2], tid);
  __syncthreads();
  const int T1 = ctl[2];
  for (int i = tid; i < CA; i += MEGA_T) {
    int ci = u.s.candA[i];
    int s = u.s.cidx[ci];
    uint32_t k = fkey(lw[s] + gumbel_precise(row, s));
    int mid = (int)((k >> 10) & 0x7FFu);
    if (mid > T1)       { int p = atomicAdd(&ctl[0], 1); outrow[p] = s; }
    else if (mid == T1) { int c = atomicAdd(&ctl[4], 1); if (c < 256) u.s.candB[c] = (uint16_t)ci; }
  }
  __syncthreads();
  const int CB = min(ctl[4], 256);
  for (int i = tid; i < 1024; i += MEGA_T) u.s.hist[i] = 0;
  __syncthreads();
  for (int i = tid; i < CB; i += MEGA_T) {
    int s = u.s.cidx[u.s.candB[i]];
    uint32_t k = fkey(lw[s] + gumbel_precise(row, s));
    atomicAdd(&u.s.hist[k & 0x3FFu], 1u);
  }
  __syncthreads();
  find_thresh(u.s.hist, 1024, 16, (uint32_t)(NS - ctl[0]), &ctl[2], tid);
  __syncthreads();
  const int T2 = ctl[2];
  for (int i = tid; i < CB; i += MEGA_T) {
    int ci = u.s.candB[i];
    int s = u.s.cidx[ci];
    uint32_t k = fkey(lw[s] + gumbel_precise(row, s));
    int lo = (int)(k & 0x3FFu);
    if (lo > T2)       { int p = atomicAdd(&ctl[0], 1); outrow[p] = s; }
    else if (lo == T2) { int c = atomicAdd(&ctl[5], 1); if (c < 64) u.s.candC[c] = (uint16_t)ci; }
  }
  __syncthreads();
  if (tid == 0) {
    int need = NS - ctl[0];
    int cc = min(ctl[5], 64);
    for (int k = 0; k < need; ++k) {   // exact-key ties: smallest index first (top_k semantics)
      int best = 0x7fffffff, bi = 0;
      for (int j = 0; j < cc; ++j) { int s = u.s.cidx[u.s.candC[j]]; if (s < best) { best = s; bi = j; } }
      if (best == 0x7fffffff) best = 0;
      outrow[ctl[0] + k] = best;
      if (cc > 0) u.s.cidx[u.s.candC[bi]] = 0x7fffffff;
    }
  }
  __syncthreads();

  // ---------------- attn: scores -> softmax -> lerp + winner ----------------
  const f32x4* K4 = (const f32x4*)Kst;
  const f32x4* V4 = (const f32x4*)Vst;
  const int lane = tid & 63, wv = tid >> 6;   // 8 waves
  const int sj = lane >> 3, dj = lane & 7;
  for (int i = tid; i < NS; i += MEGA_T) u.a.sel_s[i] = outrow[i];
  const f32x4* q4 = (const f32x4*)(qin + (size_t)row * ND);
  f32x4 qa = q4[dj * 2], qb = q4[dj * 2 + 1];
  __syncthreads();
  // phase 1: 8 scores per wave per iter, unroll 2
  for (int it = 0; it < 16; it += 2) {
    int i1 = it * 64 + wv * 8 + sj;
    int i2 = i1 + 64;
    int x1 = u.a.sel_s[i1], x2 = u.a.sel_s[i2];
    size_t b1 = ((size_t)x1 * NH + h) * 16 + dj * 2;
    size_t b2 = ((size_t)x2 * NH + h) * 16 + dj * 2;
    f32x4 ka1 = K4[b1], kb1 = K4[b1 + 1];
    f32x4 ka2 = K4[b2], kb2 = K4[b2 + 1];
    float p1 = ka1.x*qa.x + ka1.y*qa.y + ka1.z*qa.z + ka1.w*qa.w
             + kb1.x*qb.x + kb1.y*qb.y + kb1.z*qb.z + kb1.w*qb.w;
    float p2 = ka2.x*qa.x + ka2.y*qa.y + ka2.z*qa.z + ka2.w*qa.w
             + kb2.x*qb.x + kb2.y*qb.y + kb2.z*qb.z + kb2.w*qb.w;
#pragma unroll
    for (int off = 1; off < 8; off <<= 1) { p1 += __shfl_xor(p1, off); p2 += __shfl_xor(p2, off); }
    if (dj == 0) { u.a.sc[i1] = p1 * 0.125f; u.a.sc[i2] = p2 * 0.125f; }
  }
  __syncthreads();
  // softmax (2 scores per thread)
  float v1 = u.a.sc[tid], v2 = u.a.sc[tid + 512];
  u.a.red[tid] = fmaxf(v1, v2); __syncthreads();
  for (int s = 256; s; s >>= 1) { if (tid < s) u.a.red[tid] = fmaxf(u.a.red[tid], u.a.red[tid + s]); __syncthreads(); }
  float m = u.a.red[0]; __syncthreads();
  float e1 = expf(v1 - m), e2 = expf(v2 - m);
  u.a.red[tid] = e1 + e2; __syncthreads();
  for (int s = 256; s; s >>= 1) { if (tid < s) u.a.red[tid] += u.a.red[tid + s]; __syncthreads(); }
  float inv = 1.0f / u.a.red[0];
  float a1 = e1 * inv, a2 = e2 * inv;
  u.a.sc[tid] = a1; u.a.sc[tid + 512] = a2;
  attn_ws[(size_t)row * NS + tid] = a1;
  attn_ws[(size_t)row * NS + tid + 512] = a2;
  __syncthreads();
  // phase 2: lerp accumulation
  f32x4 AK = 0.f, BK = 0.f, AV = 0.f, BV = 0.f;
  for (int it = 0; it < 16; it += 2) {
    int i1 = it * 64 + wv * 8 + sj;
    int i2 = i1 + 64;
    int x1 = u.a.sel_s[i1], x2 = u.a.sel_s[i2];
    float c1 = u.a.sc[i1], c2 = u.a.sc[i2];
    size_t b1 = ((size_t)x1 * NH + h) * 16 + dj * 2;
    size_t b2 = ((size_t)x2 * NH + h) * 16 + dj * 2;
    f32x4 k1a = K4[b1], k1b = K4[b1 + 1], v1a = V4[b1], v1b = V4[b1 + 1];
    f32x4 k2a = K4[b2], k2b = K4[b2 + 1], v2a = V4[b2], v2b = V4[b2 + 1];
    AK += c1 * k1a + c2 * k2a; BK += c1 * k1b + c2 * k2b;
    AV += c1 * v1a + c2 * v2a; BV += c1 * v1b + c2 * v2b;
  }
#pragma unroll
  for (int off = 8; off < 64; off <<= 1) {
    AK.x += __shfl_xor(AK.x, off); AK.y += __shfl_xor(AK.y, off);
    AK.z += __shfl_xor(AK.z, off); AK.w += __shfl_xor(AK.w, off);
    BK.x += __shfl_xor(BK.x, off); BK.y += __shfl_xor(BK.y, off);
    BK.z += __shfl_xor(BK.z, off); BK.w += __shfl_xor(BK.w, off);
    AV.x += __shfl_xor(AV.x, off); AV.y += __shfl_xor(AV.y, off);
    AV.z += __shfl_xor(AV.z, off); AV.w += __shfl_xor(AV.w, off);
    BV.x += __shfl_xor(BV.x, off); BV.y += __shfl_xor(BV.y, off);
    BV.z += __shfl_xor(BV.z, off); BV.w += __shfl_xor(BV.w, off);
  }
  if (sj == 0) {
    u.a.pk4[wv][dj * 2] = AK; u.a.pk4[wv][dj * 2 + 1] = BK;
    u.a.pv4[wv][dj * 2] = AV; u.a.pv4[wv][dj * 2 + 1] = BV;
  }
  __syncthreads();
  if (tid < 64) {
    float lk = 0.f, lv = 0.f;
    const float* pkf = (const float*)u.a.pk4;
    const float* pvf = (const float*)u.a.pv4;
#pragma unroll
    for (int ww = 0; ww < 8; ++ww) { lk += pkf[ww * 64 + tid]; lv += pvf[ww * 64 + tid]; }
    lerp_k[(size_t)row * ND + tid] = lk;
    lerp_v[(size_t)row * ND + tid] = lv;
  }
  // winner map: last-write-wins over b == max b per (idx,h)
  for (int i = tid; i < NS; i += MEGA_T) atomicMax(&winner[(size_t)u.a.sel_s[i] * NH + h], b);
}

// winning slots: record attn weight and fix outL (unique winner row per (idx,h))
__global__ void k_mark(const int* __restrict__ idx_sel, const float* __restrict__ attn_ws,
                       const int* __restrict__ winner, const float* __restrict__ Lst,
                       float* __restrict__ wa, float* __restrict__ outL) {
  int t = blockIdx.x * 256 + threadIdx.x;   // NROW*NS threads exactly
  int row = t >> 10, h = row & 15, b = row >> 4;
  int idx = idx_sel[t];
  size_t slot = (size_t)idx * NH + h;
  if (winner[slot] == b) {
    float a = attn_ws[t];
    wa[slot] = a;
    outL[slot] = 0.99f * Lst[slot] + a;
  }
}

#define TAIL_COPY_BLKS 4096
// heterogeneous tail: blend-fused copy of the SECOND half of K,V (first 4096 blocks),
// then 131072 tiny fixup blocks (first-half winner RMW) backfill as copy blocks retire.
__global__ void __launch_bounds__(256) k_tail(const f32x4* __restrict__ K4,
    const f32x4* __restrict__ V4, const int* __restrict__ winner,
    const float* __restrict__ wa, const f32x4* __restrict__ LK4,
    const f32x4* __restrict__ LV4, const int* __restrict__ idx_sel,
    const float* __restrict__ attn_ws, f32x4* __restrict__ oK4, f32x4* __restrict__ oV4) {
  const int bid = blockIdx.x;
  if (bid < TAIL_COPY_BLKS) {
    // ------- blend-fused copy of [HALF4, N4): 8 batches of 4-deep -------
    const long base = HALF4 + (long)bid * 256 + threadIdx.x;
    const long stride = (long)TAIL_COPY_BLKS * 256;       // 1,048,576 float4
    for (int r = 0; r < 8; ++r) {
      long i0 = base + (long)(4 * r) * stride;
      long i1 = i0 + stride, i2 = i0 + 2 * stride, i3 = i0 + 3 * stride;
      int s0 = (int)(i0 >> 4), s1 = (int)(i1 >> 4), s2 = (int)(i2 >> 4), s3 = (int)(i3 >> 4);
      int w0 = winner[s0], w1 = winner[s1], w2 = winner[s2], w3 = winner[s3];
      f32x4 k0 = __builtin_nontemporal_load(&K4[i0]);
      f32x4 k1 = __builtin_nontemporal_load(&K4[i1]);
      f32x4 k2 = __builtin_nontemporal_load(&K4[i2]);
      f32x4 k3 = __builtin_nontemporal_load(&K4[i3]);
      f32x4 v0 = __builtin_nontemporal_load(&V4[i0]);
      f32x4 v1 = __builtin_nontemporal_load(&V4[i1]);
      f32x4 v2 = __builtin_nontemporal_load(&V4[i2]);
      f32x4 v3 = __builtin_nontemporal_load(&V4[i3]);
      if (w0 >= 0) {
        float a = wa[s0]; int rr = (w0 << 4) | (s0 & 15); float o = 1.0f - a;
        k0 = o * k0 + a * LK4[((long)rr << 4) + (i0 & 15)];
        v0 = o * v0 + a * LV4[((long)rr << 4) + (i0 & 15)];
      }
      if (w1 >= 0) {
        float a = wa[s1]; int rr = (w1 << 4) | (s1 & 15); float o = 1.0f - a;
        k1 = o * k1 + a * LK4[((long)rr << 4) + (i1 & 15)];
        v1 = o * v1 + a * LV4[((long)rr << 4) + (i1 & 15)];
      }
      if (w2 >= 0) {
        float a = wa[s2]; int rr = (w2 << 4) | (s2 & 15); float o = 1.0f - a;
        k2 = o * k2 + a * LK4[((long)rr << 4) + (i2 & 15)];
        v2 = o * v2 + a * LV4[((long)rr << 4) + (i2 & 15)];
      }
      if (w3 >= 0) {
        float a = wa[s3]; int rr = (w3 << 4) | (s3 & 15); float o = 1.0f - a;
        k3 = o * k3 + a * LK4[((long)rr << 4) + (i3 & 15)];
        v3 = o * v3 + a * LV4[((long)rr << 4) + (i3 & 15)];
      }
      __builtin_nontemporal_store(k0, &oK4[i0]);
      __builtin_nontemporal_store(k1, &oK4[i1]);
      __builtin_nontemporal_store(k2, &oK4[i2]);
      __builtin_nontemporal_store(k3, &oK4[i3]);
      __builtin_nontemporal_store(v0, &oV4[i0]);
      __builtin_nontemporal_store(v1, &oV4[i1]);
      __builtin_nontemporal_store(v2, &oV4[i2]);
      __builtin_nontemporal_store(v3, &oV4[i3]);
    }
    return;
  }
  // ------- fixup path: winner-slot RMW for first-half slots; one wave per (row,i) -------
  int g = (bid - TAIL_COPY_BLKS) * 4 + (threadIdx.x >> 6);
  int lane = threadIdx.x & 63;
  int row = g >> 10, i = g & 1023;
  int h = row & 15, b = row >> 4;
  int idx = idx_sel[(size_t)row * NS + i];
  if (idx >= SPLIT_IDX) return;               // second half handled by blend-copy above
  size_t slot = (size_t)idx * NH + h;
  if (winner[slot] != b) return;
  float a = attn_ws[(size_t)row * NS + i];
  size_t base = slot * (size_t)ND + lane;
  float kv = ((const float*)K4)[base], vv = ((const float*)V4)[base];
  float lk = ((const float*)LK4)[(size_t)row * ND + lane];
  float lv = ((const float*)LV4)[(size_t)row * ND + lane];
  float o = 1.0f - a;
  ((float*)oK4)[base] = o * kv + a * lk;
  ((float*)oV4)[base] = o * vv + a * lv;
}

extern "C" void kernel_launch(void* const* d_in, const int* in_sizes, int n_in,
                              void* d_out, int out_size, void* d_ws, size_t ws_size,
                              hipStream_t stream) {
  const float* q   = (const float*)d_in[0];
  const float* Kst = (const float*)d_in[1];
  const float* Vst = (const float*)d_in[2];
  const float* Lst = (const float*)d_in[3];

  float* out    = (float*)d_out;
  float* out_lk = out;                        // (B,H,D)
  float* out_lv = out + 32768;
  float* outK   = out + 65536;                // (SIZE,H,D)
  float* outV   = outK + 268435456;
  float* outL   = outV + 268435456;           // (SIZE,H)

  char* ws = (char*)d_ws;
  float* logw   = (float*)ws;                         // 16 MB (H,SIZE)
  float* wexp   = (float*)(ws + (16ull << 20));       // 16 MB (H,SIZE)
  int*   idxsel = (int*)(ws + (32ull << 20));         //  2 MB (NROW,NS)
  float* attn   = (float*)(ws + (34ull << 20));       //  2 MB
  int*   winner = (int*)(ws + (36ull << 20));         // 16 MB (SIZE,H)
  float* wa     = (float*)(ws + (52ull << 20));       // 16 MB (SIZE,H)
  float* Wsum   = (float*)(ws + (68ull << 20));       // 64 B  (H)

  hipMemsetAsync(Wsum, 0, 16 * sizeof(float), stream);
  k_logw<<<SZ / 256, 256, 0, stream>>>(Lst, logw, wexp, outL, winner, Wsum);
  k_mega<<<SEL_BLKS + COPY_BLKS, MEGA_T, 0, stream>>>(logw, wexp, Wsum, q, Kst, Vst,
                                                      idxsel, attn, out_lk, out_lv, winner,
                                                      (f32x4*)outK, (f32x4*)outV);
  k_mark<<<NROW * NS / 256, 256, 0, stream>>>(idxsel, attn, winner, Lst, wa, outL);
  k_tail<<<TAIL_COPY_BLKS + NROW * NS / 4, 256, 0, stream>>>(
      (const f32x4*)Kst, (const f32x4*)Vst, winner, wa,
      (const f32x4*)out_lk, (const f32x4*)out_lv, idxsel, attn,
      (f32x4*)outK, (f32x4*)outV);
}